// Round 7
// baseline (396.352 us; speedup 1.0000x reference)
//
#include <hip/hip_runtime.h>
#include <hip/hip_bf16.h>
#include <math.h>

// TFAlbertAttention  B=4,S=2048,D=1024,H=16,DH=64, fp32 in/out.
// cast->bf16, 128-tile MFMA GEMMs w/ global_load_lds staging, barrier-free
// flash attention (1-wave blocks, direct-global K/V fragments, m=0 softmax,
// exp2-fma, cross-lane l reduction), out GEMM (bf16), fused residual+LN.

#define B_ 4
#define S_ 2048
#define D_ 1024
#define H_ 16
#define DH_ 64
#define LN_EPS 1e-12f

typedef __attribute__((ext_vector_type(8))) short short8_;
typedef __attribute__((ext_vector_type(4))) short short4_;
typedef __attribute__((ext_vector_type(4))) float float4_;

__device__ inline short f2b(float x) {          // RNE
    unsigned u = __float_as_uint(x);
    unsigned r = (u + 0x7fffu + ((u >> 16) & 1u)) >> 16;
    return (short)r;
}
__device__ inline short f2b_trunc(float x) {    // truncate (P only)
    return (short)(__float_as_uint(x) >> 16);
}

__device__ inline float4_ mfma16(short8_ a, short8_ b, float4_ c) {
    return __builtin_amdgcn_mfma_f32_16x16x32_bf16(a, b, c, 0, 0, 0);
}

#define GLOAD16(g, l)                                                      \
    __builtin_amdgcn_global_load_lds(                                      \
        (const __attribute__((address_space(1))) void*)(g),                \
        (__attribute__((address_space(3))) void*)(l), 16, 0, 0)

// ---------------- weight transpose + cast: W[k][n] fp32 -> Wt[n][k] bf16 ----
__global__ __launch_bounds__(256) void prep_weights(
    const float* __restrict__ W0, const float* __restrict__ W1,
    const float* __restrict__ W2, const float* __restrict__ W3,
    short* __restrict__ Wt)
{
    const float* W = (blockIdx.z == 0) ? W0 : (blockIdx.z == 1) ? W1
                   : (blockIdx.z == 2) ? W2 : W3;
    short* out = Wt + (size_t)blockIdx.z * (1024 * 1024);
    __shared__ float T[64][65];
    int tx = threadIdx.x & 63, ty = threadIdx.x >> 6;
    int k0 = blockIdx.x * 64, n0 = blockIdx.y * 64;
#pragma unroll
    for (int i = 0; i < 16; i++) {
        int kk = ty + i * 4;
        T[kk][tx] = W[(size_t)(k0 + kk) * 1024 + n0 + tx];
    }
    __syncthreads();
#pragma unroll
    for (int i = 0; i < 16; i++) {
        int nn = ty + i * 4;
        out[(size_t)(n0 + nn) * 1024 + k0 + tx] = f2b(T[tx][nn]);
    }
}

// ---------------- x fp32 -> bf16 ----------------
__global__ __launch_bounds__(256) void cast_x(const float* __restrict__ x,
                                              short* __restrict__ xb)
{
    int i = blockIdx.x * 256 + threadIdx.x;
    float4_ v = ((const float4_*)x)[i];
    short4_ o;
#pragma unroll
    for (int j = 0; j < 4; j++) o[j] = f2b(v[j]);
    ((short4_*)xb)[i] = o;
}

// ---------------- 128x128-tile GEMM: C = A[M,K] * Bt[N,K]^T + bias ---------
// MODE 1: bf16 out [m][n]; MODE 2: bf16 out transposed per-head -> Vtg[bh][dh][s].
template <int MODE>
__global__ __launch_bounds__(256) void gemm128(
    const short* __restrict__ A, const short* __restrict__ Bt,
    const float* __restrict__ bias, void* __restrict__ Cout,
    int M, int N, int K)
{
    __shared__ __align__(16) short As[128 * 32];
    __shared__ __align__(16) short Bs[128 * 32];
    int tid = threadIdx.x;
    int wv = tid >> 6, lane = tid & 63;
    int g = lane >> 4, ln = lane & 15;
    int wm = wv & 1, wn = wv >> 1;
    int mtile = blockIdx.x * 128, ntile = blockIdx.y * 128;

    int srow = wv * 32 + (lane >> 2);
    int scol = (lane & 3) * 8;
    const short* agp = A + (size_t)(mtile + srow) * K + scol;
    const short* bgp = Bt + (size_t)(ntile + srow) * K + scol;
    short* alp0 = &As[(wv * 32) * 32];
    short* alp1 = &As[(wv * 32 + 16) * 32];
    short* blp0 = &Bs[(wv * 32) * 32];
    short* blp1 = &Bs[(wv * 32 + 16) * 32];

    float4_ acc[4][4];
#pragma unroll
    for (int i = 0; i < 4; i++)
#pragma unroll
        for (int j = 0; j < 4; j++) acc[i][j] = (float4_)(0.f);

    for (int k0 = 0; k0 < K; k0 += 32) {
        if (k0) __syncthreads();
        GLOAD16(agp + k0, alp0);
        GLOAD16(agp + k0 + (size_t)16 * K, alp1);
        GLOAD16(bgp + k0, blp0);
        GLOAD16(bgp + k0 + (size_t)16 * K, blp1);
        __syncthreads();
        short8_ am[4], bn[4];
#pragma unroll
        for (int mt = 0; mt < 4; mt++)
            am[mt] = *(const short8_*)(&As[(wm * 64 + mt * 16 + ln) * 32 + g * 8]);
#pragma unroll
        for (int nt = 0; nt < 4; nt++)
            bn[nt] = *(const short8_*)(&Bs[(wn * 64 + nt * 16 + ln) * 32 + g * 8]);
#pragma unroll
        for (int mt = 0; mt < 4; mt++)
#pragma unroll
            for (int nt = 0; nt < 4; nt++)
                acc[mt][nt] = mfma16(am[mt], bn[nt], acc[mt][nt]);
    }

    if constexpr (MODE == 2) {
        __shared__ __align__(16) short T[64][132];
        int b = mtile >> 11, s0 = mtile & 2047;
        short* Vtg = (short*)Cout;
#pragma unroll
        for (int p = 0; p < 2; p++) {
            __syncthreads();
            if (wn == p) {
#pragma unroll
                for (int nt = 0; nt < 4; nt++) {
                    float bsv = bias[ntile + p * 64 + nt * 16 + ln];
#pragma unroll
                    for (int mt = 0; mt < 4; mt++) {
                        short4_ o;
#pragma unroll
                        for (int r = 0; r < 4; r++) o[r] = f2b(acc[mt][nt][r] + bsv);
                        *(short4_*)(&T[nt * 16 + ln][wm * 64 + mt * 16 + g * 4]) = o;
                    }
                }
            }
            __syncthreads();
            int h = (ntile >> 6) + p;
            int row = tid >> 2, colb = (tid & 3) * 32;
            size_t obase = ((size_t)(b * H_ + h)) * (DH_ * S_) + (size_t)row * S_ + s0 + colb;
#pragma unroll
            for (int c = 0; c < 4; c++)
                *(short8_*)(Vtg + obase + c * 8) = *(const short8_*)(&T[row][colb + c * 8]);
        }
    } else {
#pragma unroll
        for (int nt = 0; nt < 4; nt++) {
            int n = ntile + wn * 64 + nt * 16 + ln;
            float bsv = bias[n];
#pragma unroll
            for (int mt = 0; mt < 4; mt++) {
#pragma unroll
                for (int r = 0; r < 4; r++) {
                    int m = mtile + wm * 64 + mt * 16 + g * 4 + r;
                    ((short*)Cout)[(size_t)m * N + n] = f2b(acc[mt][nt][r] + bsv);
                }
            }
        }
    }
}

// ---------------- barrier-free flash attention -----------------------------
// grid (S/64, B*H), block = 64 threads = 1 wave. Wave owns 64 q rows
// (4 groups of 16). K/V MFMA fragments loaded directly from global
// (contiguous 16B runs); LDS used only for the P C->A layout round trip.
__global__ __launch_bounds__(64) void attn(
    const short* __restrict__ Qb, const short* __restrict__ Kb,
    const short* __restrict__ Vtg, const float* __restrict__ mask,
    short* __restrict__ ctx)
{
    __shared__ __align__(16) short Pb[64][72];
    int lane = threadIdx.x;
    int g = lane >> 4, ln = lane & 15;
    int qt = blockIdx.x, bh = blockIdx.y;
    int b = bh >> 4, h = bh & 15;
    const size_t base = (size_t)b * S_ * D_ + h * DH_;
    const size_t vbase = (size_t)bh * (DH_ * S_);
    const float C1 = 0.18033688f;       // 0.125 * log2(e)
    const float LOG2E = 1.44269504f;

    short8_ aq[4][2];
#pragma unroll
    for (int qg = 0; qg < 4; qg++) {
        int qrow = qt * 64 + qg * 16 + ln;
        aq[qg][0] = *(const short8_*)(Qb + base + (size_t)qrow * D_ + g * 8);
        aq[qg][1] = *(const short8_*)(Qb + base + (size_t)qrow * D_ + 32 + g * 8);
    }

    float4_ O[4][4];
    float lp[4][4];
#pragma unroll
    for (int qg = 0; qg < 4; qg++)
#pragma unroll
        for (int i = 0; i < 4; i++) { O[qg][i] = (float4_)(0.f); lp[qg][i] = 0.f; }

    for (int kt = 0; kt < S_ / 64; kt++) {
        int kb = kt * 64;
        // K fragments: B-operand rows = keys, contiguous 16B in dh
        short8_ kf[4][2];
#pragma unroll
        for (int nt = 0; nt < 4; nt++) {
            const short* kp = Kb + base + (size_t)(kb + nt * 16 + ln) * D_;
            kf[nt][0] = *(const short8_*)(kp + g * 8);
            kf[nt][1] = *(const short8_*)(kp + 32 + g * 8);
        }
        // V fragments: B-operand rows = dh, contiguous 16B in key
        short8_ vf[2][4];
#pragma unroll
        for (int ks = 0; ks < 2; ks++)
#pragma unroll
            for (int dt = 0; dt < 4; dt++)
                vf[ks][dt] = *(const short8_*)(
                    Vtg + vbase + (size_t)(dt * 16 + ln) * S_ + kb + ks * 32 + g * 8);
        float mk2[4];
#pragma unroll
        for (int nt = 0; nt < 4; nt++)
            mk2[nt] = mask[(size_t)b * S_ + kb + nt * 16 + ln] * LOG2E;

#pragma unroll
        for (int qg = 0; qg < 4; qg++) {
            float4_ Sf[4];
#pragma unroll
            for (int nt = 0; nt < 4; nt++) {
                float4_ s = (float4_)(0.f);
                s = mfma16(aq[qg][0], kf[nt][0], s);
                s = mfma16(aq[qg][1], kf[nt][1], s);
                Sf[nt] = s;
            }
#pragma unroll
            for (int nt = 0; nt < 4; nt++)
#pragma unroll
                for (int r = 0; r < 4; r++) {
                    float p = __builtin_amdgcn_exp2f(fmaf(Sf[nt][r], C1, mk2[nt]));
                    lp[qg][r] += p;
                    Pb[qg * 16 + g * 4 + r][nt * 16 + ln] = f2b_trunc(p);
                }
        }
        __syncthreads();   // single-wave block: cheap; forces P visibility

#pragma unroll
        for (int ks = 0; ks < 2; ks++)
#pragma unroll
            for (int qg = 0; qg < 4; qg++) {
                short8_ pa = *(const short8_*)(&Pb[qg * 16 + ln][ks * 32 + g * 8]);
#pragma unroll
                for (int dt = 0; dt < 4; dt++)
                    O[qg][dt] = mfma16(pa, vf[ks][dt], O[qg][dt]);
            }
        __syncthreads();   // WAR guard before next tile's P writes
    }

    // lp holds per-lane partials (keys ≡ ln mod 16) — reduce across ln lanes
#pragma unroll
    for (int qg = 0; qg < 4; qg++) {
        float inv[4];
#pragma unroll
        for (int r = 0; r < 4; r++) {
            float s = lp[qg][r];
#pragma unroll
            for (int sh = 1; sh < 16; sh <<= 1) s += __shfl_xor(s, sh);
            inv[r] = 1.f / s;
        }
#pragma unroll
        for (int dt = 0; dt < 4; dt++)
#pragma unroll
            for (int r = 0; r < 4; r++) {
                int q = qt * 64 + qg * 16 + g * 4 + r;
                float v = O[qg][dt][r] * inv[r];
                ctx[base + (size_t)q * D_ + dt * 16 + ln] = f2b(v);
            }
    }
}

// ---------------- residual + LayerNorm (h in bf16) -------------------------
__global__ __launch_bounds__(256) void ln_kernel(
    const short* __restrict__ hb, const float* __restrict__ x,
    const float* __restrict__ gamma, const float* __restrict__ beta,
    float* __restrict__ out)
{
    int row = blockIdx.x, tid = threadIdx.x;
    const short* hr = hb + (size_t)row * D_;
    const float* xr = x + (size_t)row * D_;
    short4_ h4 = ((const short4_*)hr)[tid];
    float4_ x4 = ((const float4_*)xr)[tid];
    float y[4], s1 = 0.f, s2 = 0.f;
#pragma unroll
    for (int i = 0; i < 4; i++) {
        float hv = __uint_as_float(((unsigned)(unsigned short)h4[i]) << 16);
        float v = hv + x4[i];
        y[i] = v;
        s1 += v;
        s2 += v * v;
    }
#pragma unroll
    for (int sh = 1; sh < 64; sh <<= 1) {
        s1 += __shfl_xor(s1, sh);
        s2 += __shfl_xor(s2, sh);
    }
    __shared__ float ws1[4], ws2[4];
    if ((tid & 63) == 0) { ws1[tid >> 6] = s1; ws2[tid >> 6] = s2; }
    __syncthreads();
    s1 = ws1[0] + ws1[1] + ws1[2] + ws1[3];
    s2 = ws2[0] + ws2[1] + ws2[2] + ws2[3];
    float mu = s1 * (1.f / D_);
    float var = s2 * (1.f / D_) - mu * mu;
    float rs = rsqrtf(var + LN_EPS);
    float4_ g4 = ((const float4_*)gamma)[tid];
    float4_ b4 = ((const float4_*)beta)[tid];
    float4_ o4;
#pragma unroll
    for (int i = 0; i < 4; i++) o4[i] = (y[i] - mu) * rs * g4[i] + b4[i];
    ((float4_*)(out + (size_t)row * D_))[tid] = o4;
}

extern "C" void kernel_launch(void* const* d_in, const int* in_sizes, int n_in,
                              void* d_out, int out_size, void* d_ws, size_t ws_size,
                              hipStream_t stream)
{
    const float* x     = (const float*)d_in[0];
    const float* mask  = (const float*)d_in[1];
    const float* Wq    = (const float*)d_in[2];
    const float* bq    = (const float*)d_in[3];
    const float* Wk    = (const float*)d_in[4];
    const float* bk    = (const float*)d_in[5];
    const float* Wv    = (const float*)d_in[6];
    const float* bv    = (const float*)d_in[7];
    const float* Wo    = (const float*)d_in[8];
    const float* bo    = (const float*)d_in[9];
    const float* gamma = (const float*)d_in[10];
    const float* beta  = (const float*)d_in[11];
    float* out = (float*)d_out;

    char* ws = (char*)d_ws;
    const size_t MB = 1024 * 1024;
    short* Wt  = (short*)(ws);              // 8 MB
    short* Xb  = (short*)(ws + 8 * MB);     // 16 MB (reused for Ctx)
    short* Qb  = (short*)(ws + 24 * MB);    // 16 MB (reused for Hh)
    short* Kb  = (short*)(ws + 40 * MB);    // 16 MB
    short* Vtg = (short*)(ws + 56 * MB);    // 16 MB, [bh][dh][s]
    short* Ctx = Xb;
    short* Hh  = Qb;                        // Qb dead after attn

    prep_weights<<<dim3(16, 16, 4), 256, 0, stream>>>(Wq, Wk, Wv, Wo, Wt);
    cast_x<<<(B_ * S_ * D_) / (256 * 4), 256, 0, stream>>>(x, Xb);

    const int M = B_ * S_, N = D_, K = D_;
    dim3 ggrid(M / 128, N / 128);
    gemm128<1><<<ggrid, 256, 0, stream>>>(Xb, Wt,               bq, Qb,  M, N, K);
    gemm128<1><<<ggrid, 256, 0, stream>>>(Xb, Wt + 1 * 1048576, bk, Kb,  M, N, K);
    gemm128<2><<<ggrid, 256, 0, stream>>>(Xb, Wt + 2 * 1048576, bv, Vtg, M, N, K);

    attn<<<dim3(S_ / 64, B_ * H_), 64, 0, stream>>>(Qb, Kb, Vtg, mask, Ctx);

    gemm128<1><<<ggrid, 256, 0, stream>>>(Ctx, Wt + 3 * 1048576, bo, Hh, M, N, K);

    ln_kernel<<<B_ * S_, 256, 0, stream>>>(Hh, x, gamma, beta, out);
}

// Round 8
// 321.400 us; speedup vs baseline: 1.2332x; 1.2332x over previous
//
#include <hip/hip_runtime.h>
#include <hip/hip_bf16.h>
#include <math.h>

// TFAlbertAttention  B=4,S=2048,D=1024,H=16,DH=64, fp32 in/out.
// cast->bf16, 128-tile MFMA GEMMs (BK=64, 2x32 sub-buffers, global_load_lds),
// flash attention (4-wave blocks, LDS-staged K/V, m=0 softmax, exp2-fma),
// out GEMM (bf16), fused residual+LayerNorm.

#define B_ 4
#define S_ 2048
#define D_ 1024
#define H_ 16
#define DH_ 64
#define LN_EPS 1e-12f

typedef __attribute__((ext_vector_type(8))) short short8_;
typedef __attribute__((ext_vector_type(4))) short short4_;
typedef __attribute__((ext_vector_type(4))) float float4_;

__device__ inline short f2b(float x) {          // RNE
    unsigned u = __float_as_uint(x);
    unsigned r = (u + 0x7fffu + ((u >> 16) & 1u)) >> 16;
    return (short)r;
}
__device__ inline short f2b_trunc(float x) {    // truncate (P only)
    return (short)(__float_as_uint(x) >> 16);
}

__device__ inline float4_ mfma16(short8_ a, short8_ b, float4_ c) {
    return __builtin_amdgcn_mfma_f32_16x16x32_bf16(a, b, c, 0, 0, 0);
}

#define GLOAD16(g, l)                                                      \
    __builtin_amdgcn_global_load_lds(                                      \
        (const __attribute__((address_space(1))) void*)(g),                \
        (__attribute__((address_space(3))) void*)(l), 16, 0, 0)

// ---------------- weight transpose + cast: W[k][n] fp32 -> Wt[n][k] bf16 ----
__global__ __launch_bounds__(256) void prep_weights(
    const float* __restrict__ W0, const float* __restrict__ W1,
    const float* __restrict__ W2, const float* __restrict__ W3,
    short* __restrict__ Wt)
{
    const float* W = (blockIdx.z == 0) ? W0 : (blockIdx.z == 1) ? W1
                   : (blockIdx.z == 2) ? W2 : W3;
    short* out = Wt + (size_t)blockIdx.z * (1024 * 1024);
    __shared__ float T[64][65];
    int tx = threadIdx.x & 63, ty = threadIdx.x >> 6;
    int k0 = blockIdx.x * 64, n0 = blockIdx.y * 64;
#pragma unroll
    for (int i = 0; i < 16; i++) {
        int kk = ty + i * 4;
        T[kk][tx] = W[(size_t)(k0 + kk) * 1024 + n0 + tx];
    }
    __syncthreads();
#pragma unroll
    for (int i = 0; i < 16; i++) {
        int nn = ty + i * 4;
        out[(size_t)(n0 + nn) * 1024 + k0 + tx] = f2b(T[tx][nn]);
    }
}

// ---------------- x fp32 -> bf16 ----------------
__global__ __launch_bounds__(256) void cast_x(const float* __restrict__ x,
                                              short* __restrict__ xb)
{
    int i = blockIdx.x * 256 + threadIdx.x;
    float4_ v = ((const float4_*)x)[i];
    short4_ o;
#pragma unroll
    for (int j = 0; j < 4; j++) o[j] = f2b(v[j]);
    ((short4_*)xb)[i] = o;
}

// ---------------- 128x128-tile GEMM: C = A[M,K] * Bt[N,K]^T + bias ---------
// BK=64 staged as two 128x32 sub-buffers (one barrier pair per 64 K).
// MODE 1: bf16 out [m][n]; MODE 2: bf16 out transposed per-head -> Vtg[bh][dh][s].
template <int MODE>
__global__ __launch_bounds__(256) void gemm128(
    const short* __restrict__ A, const short* __restrict__ Bt,
    const float* __restrict__ bias, void* __restrict__ Cout,
    int M, int N, int K)
{
    __shared__ __align__(16) short As[2][128 * 32];
    __shared__ __align__(16) short Bs[2][128 * 32];
    int tid = threadIdx.x;
    int wv = tid >> 6, lane = tid & 63;
    int g = lane >> 4, ln = lane & 15;
    int wm = wv & 1, wn = wv >> 1;
    int mtile = blockIdx.x * 128, ntile = blockIdx.y * 128;

    int srow = wv * 32 + (lane >> 2);
    int scol = (lane & 3) * 8;
    const short* agp = A + (size_t)(mtile + srow) * K + scol;
    const short* bgp = Bt + (size_t)(ntile + srow) * K + scol;

    float4_ acc[4][4];
#pragma unroll
    for (int i = 0; i < 4; i++)
#pragma unroll
        for (int j = 0; j < 4; j++) acc[i][j] = (float4_)(0.f);

    for (int k0 = 0; k0 < K; k0 += 64) {
        if (k0) __syncthreads();
#pragma unroll
        for (int hf = 0; hf < 2; hf++) {
            GLOAD16(agp + k0 + hf * 32, &As[hf][(wv * 32) * 32]);
            GLOAD16(agp + k0 + hf * 32 + (size_t)16 * K, &As[hf][(wv * 32 + 16) * 32]);
            GLOAD16(bgp + k0 + hf * 32, &Bs[hf][(wv * 32) * 32]);
            GLOAD16(bgp + k0 + hf * 32 + (size_t)16 * K, &Bs[hf][(wv * 32 + 16) * 32]);
        }
        __syncthreads();
#pragma unroll
        for (int hf = 0; hf < 2; hf++) {
            short8_ am[4], bn[4];
#pragma unroll
            for (int mt = 0; mt < 4; mt++)
                am[mt] = *(const short8_*)(&As[hf][(wm * 64 + mt * 16 + ln) * 32 + g * 8]);
#pragma unroll
            for (int nt = 0; nt < 4; nt++)
                bn[nt] = *(const short8_*)(&Bs[hf][(wn * 64 + nt * 16 + ln) * 32 + g * 8]);
#pragma unroll
            for (int mt = 0; mt < 4; mt++)
#pragma unroll
                for (int nt = 0; nt < 4; nt++)
                    acc[mt][nt] = mfma16(am[mt], bn[nt], acc[mt][nt]);
        }
    }

    if constexpr (MODE == 2) {
        __shared__ __align__(16) short T[64][132];
        int b = mtile >> 11, s0 = mtile & 2047;
        short* Vtg = (short*)Cout;
#pragma unroll
        for (int p = 0; p < 2; p++) {
            __syncthreads();
            if (wn == p) {
#pragma unroll
                for (int nt = 0; nt < 4; nt++) {
                    float bsv = bias[ntile + p * 64 + nt * 16 + ln];
#pragma unroll
                    for (int mt = 0; mt < 4; mt++) {
                        short4_ o;
#pragma unroll
                        for (int r = 0; r < 4; r++) o[r] = f2b(acc[mt][nt][r] + bsv);
                        *(short4_*)(&T[nt * 16 + ln][wm * 64 + mt * 16 + g * 4]) = o;
                    }
                }
            }
            __syncthreads();
            int h = (ntile >> 6) + p;
            int row = tid >> 2, colb = (tid & 3) * 32;
            size_t obase = ((size_t)(b * H_ + h)) * (DH_ * S_) + (size_t)row * S_ + s0 + colb;
#pragma unroll
            for (int c = 0; c < 4; c++)
                *(short8_*)(Vtg + obase + c * 8) = *(const short8_*)(&T[row][colb + c * 8]);
        }
    } else {
#pragma unroll
        for (int nt = 0; nt < 4; nt++) {
            int n = ntile + wn * 64 + nt * 16 + ln;
            float bsv = bias[n];
#pragma unroll
            for (int mt = 0; mt < 4; mt++) {
#pragma unroll
                for (int r = 0; r < 4; r++) {
                    int m = mtile + wm * 64 + mt * 16 + g * 4 + r;
                    ((short*)Cout)[(size_t)m * N + n] = f2b(acc[mt][nt][r] + bsv);
                }
            }
        }
    }
}

// ---------------- flash attention (m=0 softmax, exp2-fma) ------------------
// grid (S/128, B*H). block 256 = 4 waves; wave owns 32 q rows (2 groups of 16).
// K/V staged in LDS; l accumulated in-register, reduced once at the end.
__global__ __launch_bounds__(256) void attn(
    const short* __restrict__ Qb, const short* __restrict__ Kb,
    const short* __restrict__ Vtg, const float* __restrict__ mask,
    short* __restrict__ ctx)
{
    __shared__ __align__(16) short Ks[64][72];
    __shared__ __align__(16) short Vs[64][72];   // Vs[d][key]
    __shared__ __align__(16) short Pb[4][32][72];
    int tid = threadIdx.x, wv = tid >> 6, lane = tid & 63;
    int g = lane >> 4, ln = lane & 15;
    int qt = blockIdx.x, bh = blockIdx.y;
    int b = bh >> 4, h = bh & 15;
    const size_t base = (size_t)b * S_ * D_ + h * DH_;
    const size_t vbase = (size_t)bh * (DH_ * S_);
    const float C1 = 0.18033688f;       // 0.125 * log2(e)
    const float LOG2E = 1.44269504f;

    short8_ aq[2][2];
#pragma unroll
    for (int qg = 0; qg < 2; qg++) {
        int qrow = qt * 128 + wv * 32 + qg * 16 + ln;
        aq[qg][0] = *(const short8_*)(Qb + base + (size_t)qrow * D_ + g * 8);
        aq[qg][1] = *(const short8_*)(Qb + base + (size_t)qrow * D_ + 32 + g * 8);
    }

    float4_ O[2][4];
    float lp[2][4];
#pragma unroll
    for (int qg = 0; qg < 2; qg++)
#pragma unroll
        for (int i = 0; i < 4; i++) { O[qg][i] = (float4_)(0.f); lp[qg][i] = 0.f; }

    int srow = tid >> 2, scol = (tid & 3) * 16;

    for (int kt = 0; kt < S_ / 64; kt++) {
        int kb = kt * 64;
        const short* kp = Kb + base + (size_t)(kb + srow) * D_ + scol;
        const short* vp = Vtg + vbase + (size_t)srow * S_ + kb + scol;
        short8_ k0 = *(const short8_*)(kp);
        short8_ k1 = *(const short8_*)(kp + 8);
        short8_ v0 = *(const short8_*)(vp);
        short8_ v1 = *(const short8_*)(vp + 8);
        float mk2[4];
#pragma unroll
        for (int nt = 0; nt < 4; nt++)
            mk2[nt] = mask[(size_t)b * S_ + kb + nt * 16 + ln] * LOG2E;
        __syncthreads();
        *(short8_*)(&Ks[srow][scol]) = k0;
        *(short8_*)(&Ks[srow][scol + 8]) = k1;
        *(short8_*)(&Vs[srow][scol]) = v0;
        *(short8_*)(&Vs[srow][scol + 8]) = v1;
        __syncthreads();

        short8_ kf[4][2];
#pragma unroll
        for (int nt = 0; nt < 4; nt++) {
            kf[nt][0] = *(const short8_*)(&Ks[nt * 16 + ln][g * 8]);
            kf[nt][1] = *(const short8_*)(&Ks[nt * 16 + ln][32 + g * 8]);
        }

#pragma unroll
        for (int qg = 0; qg < 2; qg++) {
            float4_ Sf[4];
#pragma unroll
            for (int nt = 0; nt < 4; nt++) {
                float4_ s = (float4_)(0.f);
                s = mfma16(aq[qg][0], kf[nt][0], s);
                s = mfma16(aq[qg][1], kf[nt][1], s);
                Sf[nt] = s;
            }
#pragma unroll
            for (int nt = 0; nt < 4; nt++)
#pragma unroll
                for (int r = 0; r < 4; r++) {
                    float p = __builtin_amdgcn_exp2f(fmaf(Sf[nt][r], C1, mk2[nt]));
                    lp[qg][r] += p;
                    Pb[wv][qg * 16 + g * 4 + r][nt * 16 + ln] = f2b_trunc(p);
                }
        }

#pragma unroll
        for (int ks = 0; ks < 2; ks++) {
            short8_ vf[4];
#pragma unroll
            for (int dt = 0; dt < 4; dt++)
                vf[dt] = *(const short8_*)(&Vs[dt * 16 + ln][ks * 32 + g * 8]);
#pragma unroll
            for (int qg = 0; qg < 2; qg++) {
                short8_ pa = *(const short8_*)(&Pb[wv][qg * 16 + ln][ks * 32 + g * 8]);
#pragma unroll
                for (int dt = 0; dt < 4; dt++)
                    O[qg][dt] = mfma16(pa, vf[dt], O[qg][dt]);
            }
        }
    }

    // lp holds per-lane partials (keys ≡ ln mod 16) — reduce across ln lanes
#pragma unroll
    for (int qg = 0; qg < 2; qg++) {
        float inv[4];
#pragma unroll
        for (int r = 0; r < 4; r++) {
            float s = lp[qg][r];
#pragma unroll
            for (int sh = 1; sh < 16; sh <<= 1) s += __shfl_xor(s, sh);
            inv[r] = 1.f / s;
        }
#pragma unroll
        for (int dt = 0; dt < 4; dt++)
#pragma unroll
            for (int r = 0; r < 4; r++) {
                int q = qt * 128 + wv * 32 + qg * 16 + g * 4 + r;
                float v = O[qg][dt][r] * inv[r];
                ctx[base + (size_t)q * D_ + dt * 16 + ln] = f2b(v);
            }
    }
}

// ---------------- residual + LayerNorm (h in bf16) -------------------------
__global__ __launch_bounds__(256) void ln_kernel(
    const short* __restrict__ hb, const float* __restrict__ x,
    const float* __restrict__ gamma, const float* __restrict__ beta,
    float* __restrict__ out)
{
    int row = blockIdx.x, tid = threadIdx.x;
    const short* hr = hb + (size_t)row * D_;
    const float* xr = x + (size_t)row * D_;
    short4_ h4 = ((const short4_*)hr)[tid];
    float4_ x4 = ((const float4_*)xr)[tid];
    float y[4], s1 = 0.f, s2 = 0.f;
#pragma unroll
    for (int i = 0; i < 4; i++) {
        float hv = __uint_as_float(((unsigned)(unsigned short)h4[i]) << 16);
        float v = hv + x4[i];
        y[i] = v;
        s1 += v;
        s2 += v * v;
    }
#pragma unroll
    for (int sh = 1; sh < 64; sh <<= 1) {
        s1 += __shfl_xor(s1, sh);
        s2 += __shfl_xor(s2, sh);
    }
    __shared__ float ws1[4], ws2[4];
    if ((tid & 63) == 0) { ws1[tid >> 6] = s1; ws2[tid >> 6] = s2; }
    __syncthreads();
    s1 = ws1[0] + ws1[1] + ws1[2] + ws1[3];
    s2 = ws2[0] + ws2[1] + ws2[2] + ws2[3];
    float mu = s1 * (1.f / D_);
    float var = s2 * (1.f / D_) - mu * mu;
    float rs = rsqrtf(var + LN_EPS);
    float4_ g4 = ((const float4_*)gamma)[tid];
    float4_ b4 = ((const float4_*)beta)[tid];
    float4_ o4;
#pragma unroll
    for (int i = 0; i < 4; i++) o4[i] = (y[i] - mu) * rs * g4[i] + b4[i];
    ((float4_*)(out + (size_t)row * D_))[tid] = o4;
}

extern "C" void kernel_launch(void* const* d_in, const int* in_sizes, int n_in,
                              void* d_out, int out_size, void* d_ws, size_t ws_size,
                              hipStream_t stream)
{
    const float* x     = (const float*)d_in[0];
    const float* mask  = (const float*)d_in[1];
    const float* Wq    = (const float*)d_in[2];
    const float* bq    = (const float*)d_in[3];
    const float* Wk    = (const float*)d_in[4];
    const float* bk    = (const float*)d_in[5];
    const float* Wv    = (const float*)d_in[6];
    const float* bv    = (const float*)d_in[7];
    const float* Wo    = (const float*)d_in[8];
    const float* bo    = (const float*)d_in[9];
    const float* gamma = (const float*)d_in[10];
    const float* beta  = (const float*)d_in[11];
    float* out = (float*)d_out;

    char* ws = (char*)d_ws;
    const size_t MB = 1024 * 1024;
    short* Wt  = (short*)(ws);              // 8 MB
    short* Xb  = (short*)(ws + 8 * MB);     // 16 MB (reused for Ctx)
    short* Qb  = (short*)(ws + 24 * MB);    // 16 MB (reused for Hh)
    short* Kb  = (short*)(ws + 40 * MB);    // 16 MB
    short* Vtg = (short*)(ws + 56 * MB);    // 16 MB, [bh][dh][s]
    short* Ctx = Xb;
    short* Hh  = Qb;                        // Qb dead after attn

    prep_weights<<<dim3(16, 16, 4), 256, 0, stream>>>(Wq, Wk, Wv, Wo, Wt);
    cast_x<<<(B_ * S_ * D_) / (256 * 4), 256, 0, stream>>>(x, Xb);

    const int M = B_ * S_, N = D_, K = D_;
    dim3 ggrid(M / 128, N / 128);
    gemm128<1><<<ggrid, 256, 0, stream>>>(Xb, Wt,               bq, Qb,  M, N, K);
    gemm128<1><<<ggrid, 256, 0, stream>>>(Xb, Wt + 1 * 1048576, bk, Kb,  M, N, K);
    gemm128<2><<<ggrid, 256, 0, stream>>>(Xb, Wt + 2 * 1048576, bv, Vtg, M, N, K);

    attn<<<dim3(S_ / 128, B_ * H_), 256, 0, stream>>>(Qb, Kb, Vtg, mask, Ctx);

    gemm128<1><<<ggrid, 256, 0, stream>>>(Ctx, Wt + 3 * 1048576, bo, Hh, M, N, K);

    ln_kernel<<<B_ * S_, 256, 0, stream>>>(Hh, x, gamma, beta, out);
}